// Round 13
// baseline (149.089 us; speedup 1.0000x reference)
//
#include <hip/hip_runtime.h>
#include <hip/hip_bf16.h>
#include <math.h>

#define NCLS 10
#define NTOT 8192
#define NS 64                      // cntp slots per row (packed col+row)
#define NBLK2 544                  // pass-2 strip blocks (8*68)
#define NPMAX 9472                 // padded permuted rows upper bound
#define MAXSLOT 16                 // pass-1 top4 slots per row
#define G1 2048                    // pass-1 grid bound (early-exit)

using short8 = __attribute__((ext_vector_type(8))) short;
using f32x4  = __attribute__((ext_vector_type(4))) float;

__device__ __forceinline__ float digammaf_dev(float x) {
    float r = 0.0f;
    while (x < 6.0f) { r -= 1.0f / x; x += 1.0f; }
    float inv = 1.0f / x;
    float inv2 = inv * inv;
    float s = logf(x) - 0.5f * inv
            - inv2 * (0.083333333333f - inv2 * (0.0083333333333f - inv2 * 0.0039682539683f));
    return r + s;
}

__device__ __forceinline__ void cmpswap(float& a, float& b) {
    float lo = fminf(a, b), hi = fmaxf(a, b);
    a = lo; b = hi;
}

__device__ __forceinline__ void ins7(float v, float& b0, float& b1, float& b2, float& b3) {
    float x0 = fminf(b0, v); float c0 = fmaxf(b0, v);
    float x1 = fminf(b1, c0); float c1 = fmaxf(b1, c0);
    float x2 = fminf(b2, c1); float c2 = fmaxf(b2, c1);
    float x3 = fminf(b3, c2);
    b0 = x0; b1 = x1; b2 = x2; b3 = x3;
}

__device__ __forceinline__ void bmerge(int mk, float& v0, float& v1, float& v2, float& v3) {
    float u0 = __shfl_xor(v0, mk), u1 = __shfl_xor(v1, mk);
    float u2 = __shfl_xor(v2, mk), u3 = __shfl_xor(v3, mk);
    float m0 = fminf(v0, u3), m1 = fminf(v1, u2);
    float m2 = fminf(v2, u1), m3 = fminf(v3, u0);
    cmpswap(m0, m2); cmpswap(m1, m3);
    cmpswap(m0, m1); cmpswap(m2, m3);
    v0 = m0; v1 = m1; v2 = m2; v3 = m3;
}

__device__ __forceinline__ void gload_lds16(const void* g, void* s) {
    __builtin_amdgcn_global_load_lds((const __attribute__((address_space(1))) void*)g,
                                     (__attribute__((address_space(3))) void*)s, 16, 0, 0);
}

// Symmetric-chain panel tables. Steps: s0 LH p0 (A:lo0 x B:hi0), s1 LH p1,
// s2 HL p0 (A:hi0 x B:lo0), s3 HL p1, [x = HL + LH], s4 HH p0 (A:hi0 x B:hi0,
// A par0 reuses s2's), s5 HH p1. A staged for steps 1..3; B every step.
__constant__ const int APn_[5] = {192, 0, 64, -1, -1};  // panel for step s+1 (shorts)
__constant__ const int BPn_[5] = {64, 128, 192, 0, 64};

// per row: sq (fp32), XS[row][0..127]=hi(bf16), [128..255]=lo(bf16)
__global__ void prep_kernel(const float* __restrict__ X,
                            float* __restrict__ sq, unsigned short* __restrict__ XS) {
    int wave = threadIdx.x >> 6, lane = threadIdx.x & 63;
    int row = blockIdx.x * 4 + wave;
    float2 v = *(const float2*)(X + (size_t)row * 128 + lane * 2);
    __hip_bfloat16 h0 = __float2bfloat16(v.x);
    __hip_bfloat16 h1 = __float2bfloat16(v.y);
    float hf0 = __bfloat162float(h0), hf1 = __bfloat162float(h1);
    __hip_bfloat16 l0 = __float2bfloat16(v.x - hf0);
    __hip_bfloat16 l1 = __float2bfloat16(v.y - hf1);
    ushort2 hp, lp;
    hp.x = *(unsigned short*)&h0; hp.y = *(unsigned short*)&h1;
    lp.x = *(unsigned short*)&l0; lp.y = *(unsigned short*)&l1;
    *(ushort2*)(XS + (size_t)row * 256 + lane * 2) = hp;
    *(ushort2*)(XS + (size_t)row * 256 + 128 + lane * 2) = lp;
    float s = fmaf(v.x, v.x, v.y * v.y);
    #pragma unroll
    for (int off = 32; off > 0; off >>= 1) s += __shfl_down(s, off);
    if (lane == 0) sq[row] = s;
}

__global__ void count_kernel(const int* __restrict__ y, int* __restrict__ bcnt) {
    __shared__ int hist[NCLS];
    int t = threadIdx.x;
    if (t < NCLS) hist[t] = 0;
    __syncthreads();
    atomicAdd(&hist[y[blockIdx.x * 256 + t]], 1);
    __syncthreads();
    if (t < NCLS) bcnt[blockIdx.x * NCLS + t] = hist[t];
}

// plan: rowBase, T, nsl=min(T,16), cumBlk (2*T*nsl per class), nBlocks; cls; sOff; yP init
__global__ void plan_kernel(const int* __restrict__ bcnt, int* __restrict__ plan,
                            int* __restrict__ sOff, int* __restrict__ cls,
                            int* __restrict__ yP) {
    __shared__ int sT[NCLS], sBase[NCLS];
    const int c = threadIdx.x;
    for (int i = c; i < NPMAX; i += 256) yP[i] = -1;
    if (c < NCLS) {
        int run = 0;
        #pragma unroll 8
        for (int b = 0; b < 32; ++b) {
            sOff[b * NCLS + c] = run;
            run += bcnt[b * NCLS + c];
        }
        cls[c] = run;
        sT[c] = (run + 127) >> 7;
    }
    __syncthreads();
    if (c == 0) {
        int rowBase = 0, cum = 0;
        for (int q = 0; q < NCLS; ++q) {
            int T = sT[q];
            int nsl = (T > MAXSLOT) ? MAXSLOT : T;
            sBase[q] = rowBase;
            plan[q] = rowBase;
            plan[10 + q] = T;
            plan[20 + q] = nsl;
            plan[30 + q] = cum;
            rowBase += T << 7;
            cum += 2 * T * nsl;
        }
        plan[40] = cum;
    }
    __syncthreads();
    if (c < NCLS) {
        int rb = sBase[c];
        #pragma unroll 8
        for (int b = 0; b < 32; ++b) sOff[b * NCLS + c] += rb;
    }
}

__global__ void scatter_kernel(const int* __restrict__ y, const float* __restrict__ sq,
                               const unsigned short* __restrict__ XS,
                               const int* __restrict__ sOff,
                               unsigned short* __restrict__ XSP, float* __restrict__ sqP,
                               int* __restrict__ yP, int* __restrict__ idxP) {
    __shared__ int yloc[256];
    __shared__ int dstloc[256];
    const int b = blockIdx.x, t = threadIdx.x;
    const int gid = b * 256 + t;
    const int yv = y[gid];
    yloc[t] = yv;
    __syncthreads();
    int rank = 0;
    for (int k = 0; k < 256; ++k) rank += (k < t && yloc[k] == yv) ? 1 : 0;
    const int dst = sOff[b * NCLS + yv] + rank;
    dstloc[t] = dst;
    sqP[dst] = sq[gid];
    yP[dst] = yv;
    idxP[dst] = gid;
    __syncthreads();
    const int w = t >> 6, l = t & 63;
    for (int r = w; r < 256; r += 4) {
        int d = dstloc[r];
        *(ushort4*)(XSP + (size_t)d * 256 + l * 4) =
            *(const ushort4*)(XS + (size_t)(b * 256 + r) * 256 + l * 4);
    }
}

// Pass 1 (class-bucketed, 64x128 tiles, symmetric chain). Block ->
// (class c, i-half itile2, slot sIdx); covers j-tiles {sIdx, sIdx+nsl,...} < T.
__global__ __launch_bounds__(256, 2)
void pass1_kernel(const unsigned short* __restrict__ XSP, const int* __restrict__ yP,
                  const float* __restrict__ sqP, const int* __restrict__ plan,
                  float* __restrict__ top4pP) {
    const int bid = blockIdx.x;
    if (bid >= plan[40]) return;
    __shared__ __align__(16) char smem[49152];   // A dbuf 2x8K @0; B dbuf 2x16K @16384

    const int t = threadIdx.x;
    const int w = t >> 6, l = t & 63;
    const int wr = w >> 1, wc = w & 1;
    const int lg = l >> 4, lo16 = l & 15;

    int cc = 0;
    #pragma unroll
    for (int q = 1; q < NCLS; ++q) if (bid >= plan[30 + q]) cc = q;
    const int rowBase = plan[cc], T = plan[10 + cc], nsl = plan[20 + cc];
    const int local = bid - plan[30 + cc];
    const int sIdx = local % nsl;
    const int itile2 = local / nsl;
    const int ibase = rowBase + (itile2 >> 1) * 128 + (itile2 & 1) * 64;

    float sqi[8]; int yi[8];
    #pragma unroll
    for (int mi = 0; mi < 2; ++mi)
        #pragma unroll
        for (int r = 0; r < 4; ++r) {
            int row = ibase + wr * 32 + mi * 16 + lg * 4 + r;
            sqi[mi * 4 + r] = sqP[row];
            yi[mi * 4 + r] = yP[row];
        }

    const int swz = (lo16 & 7) << 4;
    unsigned aoff[2], boff[2];
    #pragma unroll
    for (int kk = 0; kk < 2; ++kk) {
        const int cA = (kk * 64 + lg * 16) ^ swz;
        aoff[kk] = (unsigned)((wr * 32 + lo16) * 128 + cA);
        boff[kk] = (unsigned)(16384 + (wc * 64 + lo16) * 128 + cA);
    }
    const int scol = ((t & 7) ^ ((t >> 3) & 7)) << 3;
    const int srow = t >> 3;   // 0..31

    auto STAGE_A = [&](int panel, int par) {
        const unsigned short* g = XSP + (size_t)(ibase + srow) * 256 + panel + scol;
        char* d = smem + par * 8192 + t * 16;
        gload_lds16(g, d);
        gload_lds16(g + 32 * 256, d + 4096);
    };
    auto STAGE_B = [&](int jbase, int panel, int par) {
        const unsigned short* g = XSP + (size_t)(jbase + srow) * 256 + panel + scol;
        char* d = smem + 16384 + par * 16384 + t * 16;
        gload_lds16(g, d);
        gload_lds16(g + 32 * 256, d + 4096);
        gload_lds16(g + 64 * 256, d + 8192);
        gload_lds16(g + 96 * 256, d + 12288);
    };

    float tp0[8], tp1[8], tp2[8], tp3[8];
    #pragma unroll
    for (int c = 0; c < 8; ++c) {
        tp0[c] = 1e30f; tp1[c] = 1e30f; tp2[c] = 1e30f; tp3[c] = 1e30f;
    }

    STAGE_A(128, 0);                 // lo0
    STAGE_B(rowBase + sIdx * 128, 0, 0);  // hi0
    __syncthreads();

    #pragma unroll 1
    for (int jt = sIdx; jt < T; jt += nsl) {
        const int jbase = rowBase + jt * 128;
        f32x4 accA[2][4], accB[2][4];
        f32x4 zz = {0.0f, 0.0f, 0.0f, 0.0f};
        #pragma unroll
        for (int mi = 0; mi < 2; ++mi)
            #pragma unroll
            for (int ni = 0; ni < 4; ++ni) { accA[mi][ni] = zz; accB[mi][ni] = zz; }

        #pragma unroll
        for (int s = 0; s < 6; ++s) {
            const int par = s & 1;
            if (s < 5) {
                if (APn_[s] >= 0) STAGE_A(APn_[s], (s + 1) & 1);
                STAGE_B(jbase, BPn_[s], (s + 1) & 1);
            } else if (jt + nsl < T) {
                STAGE_A(128, 0);
                STAGE_B(rowBase + (jt + nsl) * 128, 0, 0);
            }
            if (s == 4) {   // x = HL + LH (commutative -> swap-symmetric)
                #pragma unroll
                for (int mi = 0; mi < 2; ++mi)
                    #pragma unroll
                    for (int ni = 0; ni < 4; ++ni) accB[mi][ni] = accB[mi][ni] + accA[mi][ni];
            }
            #pragma unroll
            for (int kk = 0; kk < 2; ++kk) {
                short8 aF[2], bF[4];
                #pragma unroll
                for (int mi = 0; mi < 2; ++mi)
                    aF[mi] = *(const short8*)(smem + par * 8192 + aoff[kk] + mi * 2048);
                #pragma unroll
                for (int ni = 0; ni < 4; ++ni)
                    bF[ni] = *(const short8*)(smem + boff[kk] + par * 16384 + ni * 2048);
                if (s < 2) {
                    #pragma unroll
                    for (int mi = 0; mi < 2; ++mi)
                        #pragma unroll
                        for (int ni = 0; ni < 4; ++ni)
                            accA[mi][ni] = __builtin_amdgcn_mfma_f32_16x16x32_bf16(
                                aF[mi], bF[ni], accA[mi][ni], 0, 0, 0);
                } else {
                    #pragma unroll
                    for (int mi = 0; mi < 2; ++mi)
                        #pragma unroll
                        for (int ni = 0; ni < 4; ++ni)
                            accB[mi][ni] = __builtin_amdgcn_mfma_f32_16x16x32_bf16(
                                aF[mi], bF[ni], accB[mi][ni], 0, 0, 0);
                }
            }
            __syncthreads();
        }

        // fold tile into running top-4
        float sqj[4]; int yj[4];
        #pragma unroll
        for (int ni = 0; ni < 4; ++ni) {
            int col = jbase + wc * 64 + ni * 16 + lo16;
            sqj[ni] = sqP[col];
            yj[ni] = yP[col];
        }
        #pragma unroll
        for (int mi = 0; mi < 2; ++mi)
            #pragma unroll
            for (int r = 0; r < 4; ++r) {
                const int idx = mi * 4 + r;
                #pragma unroll
                for (int ni = 0; ni < 4; ++ni) {
                    float d2 = fmaf(-2.0f, accB[mi][ni][r], sqi[idx] + sqj[ni]);
                    d2 = fmaxf(d2, 0.0f);
                    float v = (yi[idx] == yj[ni]) ? d2 : 1e30f;
                    ins7(v, tp0[idx], tp1[idx], tp2[idx], tp3[idx]);
                }
            }
    }

    // cross-lane + cross-wave merge -> slot sIdx
    float* scrR = (float*)smem;   // all LDS dead
    #pragma unroll
    for (int idx = 0; idx < 8; ++idx) {
        float v0 = tp0[idx], v1 = tp1[idx], v2 = tp2[idx], v3 = tp3[idx];
        bmerge(1, v0, v1, v2, v3); bmerge(2, v0, v1, v2, v3);
        bmerge(4, v0, v1, v2, v3); bmerge(8, v0, v1, v2, v3);
        if (lo16 == 0) {
            int rl = wr * 32 + (idx >> 2) * 16 + lg * 4 + (idx & 3);
            float4 st; st.x = v0; st.y = v1; st.z = v2; st.w = v3;
            *(float4*)(scrR + rl * 8 + wc * 4) = st;
        }
    }
    __syncthreads();
    if (t < 64) {
        float4 qa = *(float4*)(scrR + t * 8);
        float4 qb = *(float4*)(scrR + t * 8 + 4);
        float b0 = qa.x, b1 = qa.y, b2 = qa.z, b3 = qa.w;
        ins7(qb.x, b0, b1, b2, b3); ins7(qb.y, b0, b1, b2, b3);
        ins7(qb.z, b0, b1, b2, b3); ins7(qb.w, b0, b1, b2, b3);
        size_t base = ((size_t)(ibase + t) * MAXSLOT + sIdx) * 4;
        top4pP[base + 0] = b0; top4pP[base + 1] = b1;
        top4pP[base + 2] = b2; top4pP[base + 3] = b3;
    }
}

__global__ void anchorP_kernel(const float* __restrict__ top4pP, const int* __restrict__ yP,
                               const int* __restrict__ idxP, const int* __restrict__ plan,
                               float* __restrict__ anchor) {
    int r = blockIdx.x * 256 + threadIdx.x;
    int yv = yP[r];
    if (yv < 0) return;
    int nsl = plan[20 + yv];
    float b0 = 1e30f, b1 = 1e30f, b2 = 1e30f, b3 = 1e30f;
    const float4* q4 = (const float4*)(top4pP + (size_t)r * MAXSLOT * 4);
    for (int s = 0; s < nsl; ++s) {
        float4 q = q4[s];
        ins7(q.x, b0, b1, b2, b3); ins7(q.y, b0, b1, b2, b3);
        ins7(q.z, b0, b1, b2, b3); ins7(q.w, b0, b1, b2, b3);
    }
    anchor[idxP[r]] = b3;
}

// Pass 2: strip-triangular count, symmetric chain, 8 waves, both-sides epilogues.
// Block = (it, sIdx): j-tiles [max(it,4s), 4s+3]. Slots: col [0,p); row [p, p+16-(p>>2)).
__global__ __launch_bounds__(512, 4)
void pass2_kernel(const unsigned short* __restrict__ XS, const float* __restrict__ sq,
                  const float* __restrict__ anchor, int* __restrict__ cntp) {
    __shared__ __align__(16) char smem[65536];   // A dbuf 2x16K @0; B dbuf 2x16K @32768

    const int t = threadIdx.x;
    const int w = t >> 6, l = t & 63;
    const int wy = w >> 1, wx = w & 1;
    const int lg = l >> 4, lo16 = l & 15;

    const int bid = blockIdx.x;
    const int wg = (bid & 7) * (NBLK2 / 8) + (bid >> 3);
    int it = 0, rem = wg;
    while (rem >= 16 - (it >> 2)) { rem -= 16 - (it >> 2); ++it; }
    const int sIdx = (it >> 2) + rem;
    const int ibase = it * 128;
    const int jt_lo = (4 * sIdx < it) ? it : 4 * sIdx;
    const int jt_hi = 4 * sIdx + 3;

    float sqi[8], anc_i[8];
    #pragma unroll
    for (int mi = 0; mi < 2; ++mi)
        #pragma unroll
        for (int r = 0; r < 4; ++r) {
            int row = ibase + wy * 32 + mi * 16 + lg * 4 + r;
            sqi[mi * 4 + r] = sq[row];
            anc_i[mi * 4 + r] = anchor[row];
        }

    const int swz = (lo16 & 7) << 4;
    unsigned aoff[2], boff[2];
    #pragma unroll
    for (int kk = 0; kk < 2; ++kk) {
        const int cA = (kk * 64 + lg * 16) ^ swz;
        aoff[kk] = (unsigned)((wy * 32 + lo16) * 128 + cA);
        boff[kk] = (unsigned)(32768 + (wx * 64 + lo16) * 128 + cA);
    }
    const int scol = ((t & 7) ^ ((t >> 3) & 7)) << 3;
    const int srow = t >> 3;   // 0..63

    auto STAGE_A = [&](int panel, int par) {
        const unsigned short* g = XS + (size_t)(ibase + srow) * 256 + panel + scol;
        char* d = smem + par * 16384 + t * 16;
        gload_lds16(g, d);
        gload_lds16(g + 64 * 256, d + 8192);
    };
    auto STAGE_B = [&](int jbase, int panel, int par) {
        const unsigned short* g = XS + (size_t)(jbase + srow) * 256 + panel + scol;
        char* d = smem + 32768 + par * 16384 + t * 16;
        gload_lds16(g, d);
        gload_lds16(g + 64 * 256, d + 8192);
    };

    int rc[8];
    #pragma unroll
    for (int c = 0; c < 8; ++c) rc[c] = 0;

    STAGE_A(128, 0);                 // lo0
    STAGE_B(jt_lo * 128, 0, 0);      // hi0
    __syncthreads();

    #pragma unroll 1
    for (int jt = jt_lo; jt <= jt_hi; ++jt) {
        const int jbase = jt * 128;
        const bool diag = (jt == it);
        f32x4 accA[2][4], accB[2][4];
        f32x4 zz = {0.0f, 0.0f, 0.0f, 0.0f};
        #pragma unroll
        for (int mi = 0; mi < 2; ++mi)
            #pragma unroll
            for (int ni = 0; ni < 4; ++ni) { accA[mi][ni] = zz; accB[mi][ni] = zz; }

        #pragma unroll
        for (int s = 0; s < 6; ++s) {
            const int par = s & 1;
            if (s < 5) {
                if (APn_[s] >= 0) STAGE_A(APn_[s], (s + 1) & 1);
                STAGE_B(jbase, BPn_[s], (s + 1) & 1);
            } else if (jt < jt_hi) {
                STAGE_A(128, 0);
                STAGE_B(jbase + 128, 0, 0);
            }
            if (s == 4) {
                #pragma unroll
                for (int mi = 0; mi < 2; ++mi)
                    #pragma unroll
                    for (int ni = 0; ni < 4; ++ni) accB[mi][ni] = accB[mi][ni] + accA[mi][ni];
            }
            #pragma unroll
            for (int kk = 0; kk < 2; ++kk) {
                short8 aF[2], bF[4];
                #pragma unroll
                for (int mi = 0; mi < 2; ++mi)
                    aF[mi] = *(const short8*)(smem + par * 16384 + aoff[kk] + mi * 2048);
                #pragma unroll
                for (int ni = 0; ni < 4; ++ni)
                    bF[ni] = *(const short8*)(smem + boff[kk] + par * 16384 + ni * 2048);
                if (s < 2) {
                    #pragma unroll
                    for (int mi = 0; mi < 2; ++mi)
                        #pragma unroll
                        for (int ni = 0; ni < 4; ++ni)
                            accA[mi][ni] = __builtin_amdgcn_mfma_f32_16x16x32_bf16(
                                aF[mi], bF[ni], accA[mi][ni], 0, 0, 0);
                } else {
                    #pragma unroll
                    for (int mi = 0; mi < 2; ++mi)
                        #pragma unroll
                        for (int ni = 0; ni < 4; ++ni)
                            accB[mi][ni] = __builtin_amdgcn_mfma_f32_16x16x32_bf16(
                                aF[mi], bF[ni], accB[mi][ni], 0, 0, 0);
                }
            }
            __syncthreads();
        }

        // both-sides count epilogue
        float sqj[4], anc_j[4];
        #pragma unroll
        for (int ni = 0; ni < 4; ++ni) {
            int col = jbase + wx * 64 + ni * 16 + lo16;
            sqj[ni] = sq[col];
            anc_j[ni] = anchor[col];
        }
        int colc[4] = {0, 0, 0, 0};
        #pragma unroll
        for (int mi = 0; mi < 2; ++mi)
            #pragma unroll
            for (int r = 0; r < 4; ++r) {
                const int idx = mi * 4 + r;
                #pragma unroll
                for (int ni = 0; ni < 4; ++ni) {
                    float d2 = fmaf(-2.0f, accB[mi][ni][r], sqi[idx] + sqj[ni]);
                    d2 = fmaxf(d2, 0.0f);
                    rc[idx] += (d2 <= anc_i[idx]) ? 1 : 0;
                    colc[ni] += (d2 <= anc_j[ni]) ? 1 : 0;
                }
            }
        if (!diag) {
            int* scrI = (int*)(smem + 49152);   // B par1, just consumed; [128][4]
            #pragma unroll
            for (int ni = 0; ni < 4; ++ni) {
                int c = colc[ni];
                c += __shfl_xor(c, 16); c += __shfl_xor(c, 32);
                if (lg == 0) scrI[(wx * 64 + ni * 16 + lo16) * 4 + wy] = c;
            }
            __syncthreads();
            if (t < 128)
                cntp[(size_t)(jbase + t) * NS + it] =
                    scrI[t * 4] + scrI[t * 4 + 1] + scrI[t * 4 + 2] + scrI[t * 4 + 3];
            __syncthreads();
        }
    }

    // block-end row-side -> packed row slot
    int* scr = (int*)smem;
    #pragma unroll
    for (int idx = 0; idx < 8; ++idx) {
        int c = rc[idx];
        c += __shfl_xor(c, 1); c += __shfl_xor(c, 2);
        c += __shfl_xor(c, 4); c += __shfl_xor(c, 8);
        if (lo16 == 0)
            scr[(wy * 32 + (idx >> 2) * 16 + lg * 4 + (idx & 3)) * 2 + wx] = c;
    }
    __syncthreads();
    const int slot_row = it + (sIdx - (it >> 2));
    if (t < 128) cntp[(size_t)(ibase + t) * NS + slot_row] = scr[t * 2] + scr[t * 2 + 1];
}

__global__ void reduce_kernel(const int* __restrict__ cntp, float* __restrict__ partials) {
    __shared__ float red[256];
    int t = threadIdx.x;
    int row = blockIdx.x * 256 + t;
    const int p = row >> 7;
    const int nvalid = p + 16 - (p >> 2);
    int s = 0;
    for (int c = 0; c < nvalid; ++c) s += cntp[(size_t)row * NS + c];
    red[t] = digammaf_dev((float)(s - 1));
    __syncthreads();
    for (int h = 128; h > 0; h >>= 1) {
        if (t < h) red[t] += red[t + h];
        __syncthreads();
    }
    if (t == 0) partials[blockIdx.x] = red[0];
}

__global__ void finalize_kernel(const float* __restrict__ partials, const int* __restrict__ cls,
                                float* __restrict__ out) {
    if (threadIdx.x == 0) {
        float acc = 0.0f;
        for (int c = 0; c < NTOT / 256; ++c) acc += partials[c];
        float Nf = (float)NTOT;
        float avg_m = acc / Nf;
        float avgNx = 0.0f;
        for (int c = 0; c < NCLS; ++c) {
            float nx = (float)cls[c];
            if (nx > 0.0f) avgNx += (nx / Nf) * digammaf_dev(nx);
        }
        float mi = digammaf_dev(Nf) - avgNx + digammaf_dev(3.0f) - avg_m;
        out[0] = fmaxf(mi / logf(2.0f), 0.0f);
    }
}

extern "C" void kernel_launch(void* const* d_in, const int* in_sizes, int n_in,
                              void* d_out, int out_size, void* d_ws, size_t ws_size,
                              hipStream_t stream) {
    const float* X = (const float*)d_in[0];
    const int* y = (const int*)d_in[1];
    float* out = (float*)d_out;

    float* sq       = (float*)d_ws;                                   // 8192
    float* anchors  = sq + NTOT;                                      // 8192
    float* partials = anchors + NTOT;                                 // 32
    int*   cls      = (int*)(partials + 32);                          // 16
    int*   bcnt     = cls + 16;                                       // 320
    int*   sOff     = bcnt + 320;                                     // 320
    int*   plan     = sOff + 320;                                     // 48
    int*   yP       = plan + 48;                                      // 9472
    int*   idxP     = yP + NPMAX;                                     // 9472
    float* sqP      = (float*)(idxP + NPMAX);                         // 9472
    unsigned short* XS  = (unsigned short*)(sqP + NPMAX);             // 8192*256 (4 MB)
    unsigned short* XSP = XS + (size_t)NTOT * 256;                    // 9472*256 (4.85 MB)
    float* top4pP   = (float*)(XSP + (size_t)NPMAX * 256);            // 9472*16*4 (2.4 MB)
    int*   cntp     = (int*)(top4pP + (size_t)NPMAX * MAXSLOT * 4);   // 8192*64 (2 MB)

    prep_kernel<<<NTOT / 4, 256, 0, stream>>>(X, sq, XS);
    count_kernel<<<NTOT / 256, 256, 0, stream>>>(y, bcnt);
    plan_kernel<<<1, 256, 0, stream>>>(bcnt, plan, sOff, cls, yP);
    scatter_kernel<<<NTOT / 256, 256, 0, stream>>>(y, sq, XS, sOff, XSP, sqP, yP, idxP);
    pass1_kernel<<<G1, 256, 0, stream>>>(XSP, yP, sqP, plan, top4pP);
    anchorP_kernel<<<NPMAX / 256, 256, 0, stream>>>(top4pP, yP, idxP, plan, anchors);
    pass2_kernel<<<NBLK2, 512, 0, stream>>>(XS, sq, anchors, cntp);
    reduce_kernel<<<NTOT / 256, 256, 0, stream>>>(cntp, partials);
    finalize_kernel<<<1, 64, 0, stream>>>(partials, cls, out);
}